// Round 16
// baseline (296.400 us; speedup 1.0000x reference)
//
#include <hip/hip_runtime.h>
#include <hip/hip_bf16.h>

// GCN 2-layer forward. N=50000 nodes, E=800000 edges, F=128, H=128, C=64.
//   y1 = (x @ W1) * dinv[row]          [bf16: gather operand]
//   h  = relu(dinv[v]*(sum y1[src] + y1[v]) + b1)   [fp32]
//   y2 = (h @ W2) * dinv[row]          [bf16: gather operand]
//   o  = dinv[v]*(sum y2[src] + y2[v]) + b2 ; out = log_softmax(o)

#define K_DIM 128

__device__ __forceinline__ ushort f2bf(float f) {          // round-to-nearest-even
    unsigned u = __float_as_uint(f);
    return (ushort)((u + 0x7FFF + ((u >> 16) & 1)) >> 16);
}
__device__ __forceinline__ float bflo(unsigned p) { return __uint_as_float(p << 16); }
__device__ __forceinline__ float bfhi(unsigned p) { return __uint_as_float(p & 0xFFFF0000u); }

// 1 edge per thread: max occupancy for the atomic latency chain.
__global__ void count_kernel(const int* __restrict__ dst, int* __restrict__ deg, int E) {
    const int e = blockIdx.x * blockDim.x + threadIdx.x;
    if (e < E) atomicAdd(&deg[dst[e]], 1);
}

// ---- 3-phase parallel exclusive scan over deg[n] ----
__global__ __launch_bounds__(256) void scan_phaseA(const int* __restrict__ deg,
        int* __restrict__ bsum, int n) {
    const int tid = threadIdx.x, lane = tid & 63, wid = tid >> 6;
    const int base = blockIdx.x * 1024 + tid * 4;
    int s = 0;
    if (base + 3 < n) {
        int4 t = *(const int4*)&deg[base];
        s = t.x + t.y + t.z + t.w;
    } else {
        for (int j = 0; j < 4; ++j) if (base + j < n) s += deg[base + j];
    }
    #pragma unroll
    for (int off = 32; off >= 1; off >>= 1) s += __shfl_xor(s, off);
    __shared__ int wtot[4];
    if (lane == 0) wtot[wid] = s;
    __syncthreads();
    if (tid == 0) bsum[blockIdx.x] = wtot[0] + wtot[1] + wtot[2] + wtot[3];
}

__global__ __launch_bounds__(64) void scan_phaseB(const int* __restrict__ bsum,
        int* __restrict__ boff, int nb) {
    const int lane = threadIdx.x;
    int carry = 0;
    for (int base = 0; base < nb; base += 64) {
        int i = base + lane;
        int v = (i < nb) ? bsum[i] : 0;
        int s = v;
        #pragma unroll
        for (int off = 1; off < 64; off <<= 1) {
            int t = __shfl_up(s, off);
            if (lane >= off) s += t;
        }
        if (i < nb) boff[i] = carry + s - v;
        carry += __shfl(s, 63);
    }
}

__global__ __launch_bounds__(256) void scan_phaseC(const int* __restrict__ deg,
        const int* __restrict__ boff, int* __restrict__ rowptr,
        int* __restrict__ fillpos, float* __restrict__ dinv, int n) {
    const int tid = threadIdx.x, lane = tid & 63, wid = tid >> 6;
    const int base = blockIdx.x * 1024 + tid * 4;
    int v0 = 0, v1 = 0, v2 = 0, v3 = 0;
    if (base + 3 < n) {
        int4 t = *(const int4*)&deg[base];
        v0 = t.x; v1 = t.y; v2 = t.z; v3 = t.w;
    } else {
        if (base     < n) v0 = deg[base];
        if (base + 1 < n) v1 = deg[base + 1];
        if (base + 2 < n) v2 = deg[base + 2];
        if (base + 3 < n) v3 = deg[base + 3];
    }
    const int s4 = v0 + v1 + v2 + v3;
    int incl = s4;
    #pragma unroll
    for (int off = 1; off < 64; off <<= 1) {
        int t = __shfl_up(incl, off);
        if (lane >= off) incl += t;
    }
    __shared__ int wtot[4];
    if (lane == 63) wtot[wid] = incl;
    __syncthreads();
    int wexc = 0;
    #pragma unroll
    for (int w = 0; w < 4; ++w) if (w < wid) wexc += wtot[w];

    const int ex = boff[blockIdx.x] + wexc + (incl - s4);
    if (blockIdx.x == 0 && tid == 0) rowptr[0] = 0;
    const int p1 = ex + v0, p2 = p1 + v1, p3 = p2 + v2, p4 = p3 + v3;
    if (base < n)     { fillpos[base]     = ex; rowptr[base + 1] = p1; dinv[base]     = rsqrtf((float)(v0 + 1)); }
    if (base + 1 < n) { fillpos[base + 1] = p1; rowptr[base + 2] = p2; dinv[base + 1] = rsqrtf((float)(v1 + 1)); }
    if (base + 2 < n) { fillpos[base + 2] = p2; rowptr[base + 3] = p3; dinv[base + 2] = rsqrtf((float)(v2 + 1)); }
    if (base + 3 < n) { fillpos[base + 3] = p3; rowptr[base + 4] = p4; dinv[base + 3] = rsqrtf((float)(v3 + 1)); }
}

// 1 edge per thread + nontemporal csrc store (tests latency vs write-amp bound).
__global__ void fill_kernel(const int* __restrict__ src, const int* __restrict__ dst,
                            int* __restrict__ fillpos, int* __restrict__ csrc, int E) {
    const int e = blockIdx.x * blockDim.x + threadIdx.x;
    if (e < E) {
        const int d = dst[e], sv = src[e];
        const int p = atomicAdd(&fillpos[d], 1);
        __builtin_nontemporal_store(sv, &csrc[p]);
    }
}

// Y[row] = (X[row] @ W) * dinv[row]; output fp32 or bf16 per template flag.
template<int NOUT, int RPT, bool BF16_OUT>
__global__ __launch_bounds__(256) void gemm_scale(const float* __restrict__ X,
        const float* __restrict__ W, const float* __restrict__ dinv,
        void* __restrict__ Yout, int nrows) {
    constexpr int K     = K_DIM;
    constexpr int CG    = NOUT / 8;       // col groups (8 cols per thread)
    constexpr int SLOTS = 256 / CG;       // row slots per block
    constexpr int ROWS  = SLOTS * RPT;    // rows per block
    constexpr int HALF  = NOUT / 2;
    __shared__ float Wl[K * NOUT];
    const int tid = threadIdx.x;

    #pragma unroll
    for (int i = tid * 4; i < K * NOUT; i += 1024)
        *(float4*)&Wl[i] = *(const float4*)&W[i];
    __syncthreads();

    const int cg = tid % CG, slot = tid / CG;
    const int c0 = cg * 4, c1 = c0 + HALF;
    const int row0 = blockIdx.x * ROWS + slot * RPT;

    int rIdx[RPT];
    #pragma unroll
    for (int r = 0; r < RPT; ++r) rIdx[r] = min(row0 + r, nrows - 1);

    float a0[RPT][4], a1[RPT][4];
    #pragma unroll
    for (int r = 0; r < RPT; ++r)
        #pragma unroll
        for (int c = 0; c < 4; ++c) { a0[r][c] = 0.f; a1[r][c] = 0.f; }

    #pragma unroll 2
    for (int k = 0; k < K; k += 4) {
        float4 xv[RPT];
        #pragma unroll
        for (int r = 0; r < RPT; ++r)
            xv[r] = *(const float4*)&X[(size_t)rIdx[r] * K + k];
        #pragma unroll
        for (int kk = 0; kk < 4; ++kk) {
            float4 wa = *(const float4*)&Wl[(k + kk) * NOUT + c0];
            float4 wb = *(const float4*)&Wl[(k + kk) * NOUT + c1];
            #pragma unroll
            for (int r = 0; r < RPT; ++r) {
                const float xs = (kk == 0) ? xv[r].x : (kk == 1) ? xv[r].y
                               : (kk == 2) ? xv[r].z : xv[r].w;
                a0[r][0] += xs * wa.x; a0[r][1] += xs * wa.y;
                a0[r][2] += xs * wa.z; a0[r][3] += xs * wa.w;
                a1[r][0] += xs * wb.x; a1[r][1] += xs * wb.y;
                a1[r][2] += xs * wb.z; a1[r][3] += xs * wb.w;
            }
        }
    }

    #pragma unroll
    for (int r = 0; r < RPT; ++r) {
        const int grow = row0 + r;
        if (grow < nrows) {
            const float dv = dinv[grow];
            if constexpr (BF16_OUT) {
                ushort* Yb = (ushort*)Yout;
                ushort4 o0, o1;
                o0.x = f2bf(a0[r][0] * dv); o0.y = f2bf(a0[r][1] * dv);
                o0.z = f2bf(a0[r][2] * dv); o0.w = f2bf(a0[r][3] * dv);
                o1.x = f2bf(a1[r][0] * dv); o1.y = f2bf(a1[r][1] * dv);
                o1.z = f2bf(a1[r][2] * dv); o1.w = f2bf(a1[r][3] * dv);
                *(ushort4*)&Yb[(size_t)grow * NOUT + c0] = o0;
                *(ushort4*)&Yb[(size_t)grow * NOUT + c1] = o1;
            } else {
                float* Yf = (float*)Yout;
                float4 o0 = make_float4(a0[r][0] * dv, a0[r][1] * dv, a0[r][2] * dv, a0[r][3] * dv);
                float4 o1 = make_float4(a1[r][0] * dv, a1[r][1] * dv, a1[r][2] * dv, a1[r][3] * dv);
                *(float4*)&Yf[(size_t)grow * NOUT + c0] = o0;
                *(float4*)&Yf[(size_t)grow * NOUT + c1] = o1;
            }
        }
    }
}

// Layer-1 aggregation over bf16 y1: quarter-wave per edge (16 lanes x 16B = 256B row),
// 2 edges unrolled per quarter (8 gathers in flight per wave).
__global__ __launch_bounds__(256) void agg_relu128(const ushort* __restrict__ Yb,
        const int* __restrict__ rowptr, const int* __restrict__ csrc,
        const float* __restrict__ dinv, const float* __restrict__ bias,
        float* __restrict__ H, int n) {
    const int lane = threadIdx.x & 63;
    const int q  = lane >> 4;            // quarter id (edge slot)
    const int li = lane & 15;            // 8-bf16 (16B) slot within row
    const int v = blockIdx.x * 4 + (threadIdx.x >> 6);
    if (v >= n) return;
    const int s = rowptr[v], e = rowptr[v + 1];
    float acc[8];
    #pragma unroll
    for (int j = 0; j < 8; ++j) acc[j] = 0.f;

    int i = s + q;
    for (; i + 4 < e; i += 8) {          // 2 edges per quarter iter
        int u0 = csrc[i], u1 = csrc[i + 4];
        uint4 wa = *(const uint4*)&Yb[(size_t)u0 * 128 + li * 8];
        uint4 wb = *(const uint4*)&Yb[(size_t)u1 * 128 + li * 8];
        acc[0] += bflo(wa.x) + bflo(wb.x); acc[1] += bfhi(wa.x) + bfhi(wb.x);
        acc[2] += bflo(wa.y) + bflo(wb.y); acc[3] += bfhi(wa.y) + bfhi(wb.y);
        acc[4] += bflo(wa.z) + bflo(wb.z); acc[5] += bfhi(wa.z) + bfhi(wb.z);
        acc[6] += bflo(wa.w) + bflo(wb.w); acc[7] += bfhi(wa.w) + bfhi(wb.w);
    }
    for (; i < e; i += 4) {
        int u = csrc[i];
        uint4 wa = *(const uint4*)&Yb[(size_t)u * 128 + li * 8];
        acc[0] += bflo(wa.x); acc[1] += bfhi(wa.x);
        acc[2] += bflo(wa.y); acc[3] += bfhi(wa.y);
        acc[4] += bflo(wa.z); acc[5] += bfhi(wa.z);
        acc[6] += bflo(wa.w); acc[7] += bfhi(wa.w);
    }
    if (q == 0) {                        // self-loop term once
        uint4 wv = *(const uint4*)&Yb[(size_t)v * 128 + li * 8];
        acc[0] += bflo(wv.x); acc[1] += bfhi(wv.x);
        acc[2] += bflo(wv.y); acc[3] += bfhi(wv.y);
        acc[4] += bflo(wv.z); acc[5] += bfhi(wv.z);
        acc[6] += bflo(wv.w); acc[7] += bfhi(wv.w);
    }
    #pragma unroll
    for (int j = 0; j < 8; ++j) {
        acc[j] += __shfl_xor(acc[j], 16);
        acc[j] += __shfl_xor(acc[j], 32);
    }
    if (q == 0) {
        float4 b0 = *(const float4*)&bias[li * 8];
        float4 b1 = *(const float4*)&bias[li * 8 + 4];
        const float dv = dinv[v];
        float4 o0 = make_float4(fmaxf(dv * acc[0] + b0.x, 0.f),
                                fmaxf(dv * acc[1] + b0.y, 0.f),
                                fmaxf(dv * acc[2] + b0.z, 0.f),
                                fmaxf(dv * acc[3] + b0.w, 0.f));
        float4 o1 = make_float4(fmaxf(dv * acc[4] + b1.x, 0.f),
                                fmaxf(dv * acc[5] + b1.y, 0.f),
                                fmaxf(dv * acc[6] + b1.z, 0.f),
                                fmaxf(dv * acc[7] + b1.w, 0.f));
        *(float4*)&H[(size_t)v * 128 + li * 8] = o0;
        *(float4*)&H[(size_t)v * 128 + li * 8 + 4] = o1;
    }
}

// Layer-2 aggregation + log_softmax over bf16 y2: eighth-wave per edge
// (8 lanes x 16B = 128B row), 2 edges unrolled (16 gathers in flight per wave).
__global__ __launch_bounds__(256) void agg_lsm64(const ushort* __restrict__ Yb,
        const int* __restrict__ rowptr, const int* __restrict__ csrc,
        const float* __restrict__ dinv, const float* __restrict__ bias,
        float* __restrict__ out, int n) {
    const int lane = threadIdx.x & 63;
    const int oct = lane >> 3;           // edge slot 0..7
    const int li  = lane & 7;            // 8-bf16 (16B) slot within 128B row
    const int v = blockIdx.x * 4 + (threadIdx.x >> 6);
    if (v >= n) return;
    const int s = rowptr[v], e = rowptr[v + 1];
    float acc[8];
    #pragma unroll
    for (int j = 0; j < 8; ++j) acc[j] = 0.f;

    int i = s + oct;
    for (; i + 8 < e; i += 16) {         // 2 edges per oct iter
        int u0 = csrc[i], u1 = csrc[i + 8];
        uint4 wa = *(const uint4*)&Yb[(size_t)u0 * 64 + li * 8];
        uint4 wb = *(const uint4*)&Yb[(size_t)u1 * 64 + li * 8];
        acc[0] += bflo(wa.x) + bflo(wb.x); acc[1] += bfhi(wa.x) + bfhi(wb.x);
        acc[2] += bflo(wa.y) + bflo(wb.y); acc[3] += bfhi(wa.y) + bfhi(wb.y);
        acc[4] += bflo(wa.z) + bflo(wb.z); acc[5] += bfhi(wa.z) + bfhi(wb.z);
        acc[6] += bflo(wa.w) + bflo(wb.w); acc[7] += bfhi(wa.w) + bfhi(wb.w);
    }
    for (; i < e; i += 8) {
        int u = csrc[i];
        uint4 wa = *(const uint4*)&Yb[(size_t)u * 64 + li * 8];
        acc[0] += bflo(wa.x); acc[1] += bfhi(wa.x);
        acc[2] += bflo(wa.y); acc[3] += bfhi(wa.y);
        acc[4] += bflo(wa.z); acc[5] += bfhi(wa.z);
        acc[6] += bflo(wa.w); acc[7] += bfhi(wa.w);
    }
    if (oct == 0) {                      // self-loop term once
        uint4 wv = *(const uint4*)&Yb[(size_t)v * 64 + li * 8];
        acc[0] += bflo(wv.x); acc[1] += bfhi(wv.x);
        acc[2] += bflo(wv.y); acc[3] += bfhi(wv.y);
        acc[4] += bflo(wv.z); acc[5] += bfhi(wv.z);
        acc[6] += bflo(wv.w); acc[7] += bfhi(wv.w);
    }
    #pragma unroll
    for (int j = 0; j < 8; ++j) {        // sum across the 8 edge slots
        acc[j] += __shfl_xor(acc[j], 8);
        acc[j] += __shfl_xor(acc[j], 16);
        acc[j] += __shfl_xor(acc[j], 32);
    }
    const float dv = dinv[v];
    float4 b0 = *(const float4*)&bias[li * 8];
    float4 b1 = *(const float4*)&bias[li * 8 + 4];
    float val[8];
    val[0] = dv * acc[0] + b0.x; val[1] = dv * acc[1] + b0.y;
    val[2] = dv * acc[2] + b0.z; val[3] = dv * acc[3] + b0.w;
    val[4] = dv * acc[4] + b1.x; val[5] = dv * acc[5] + b1.y;
    val[6] = dv * acc[6] + b1.z; val[7] = dv * acc[7] + b1.w;
    // row (64 classes) = 8 lanes (li) x 8 vals; reduce across li group (xor 1,2,4)
    float m = val[0];
    #pragma unroll
    for (int j = 1; j < 8; ++j) m = fmaxf(m, val[j]);
    m = fmaxf(m, __shfl_xor(m, 1));
    m = fmaxf(m, __shfl_xor(m, 2));
    m = fmaxf(m, __shfl_xor(m, 4));
    float ssum = 0.f;
    #pragma unroll
    for (int j = 0; j < 8; ++j) ssum += expf(val[j] - m);
    ssum += __shfl_xor(ssum, 1);
    ssum += __shfl_xor(ssum, 2);
    ssum += __shfl_xor(ssum, 4);
    const float lse = m + logf(ssum);
    if (oct == 0) {
        float4 o0 = make_float4(val[0] - lse, val[1] - lse, val[2] - lse, val[3] - lse);
        float4 o1 = make_float4(val[4] - lse, val[5] - lse, val[6] - lse, val[7] - lse);
        *(float4*)&out[(size_t)v * 64 + li * 8] = o0;
        *(float4*)&out[(size_t)v * 64 + li * 8 + 4] = o1;
    }
}

static inline size_t align_up(size_t x, size_t a) { return (x + a - 1) & ~(a - 1); }

extern "C" void kernel_launch(void* const* d_in, const int* in_sizes, int n_in,
                              void* d_out, int out_size, void* d_ws, size_t ws_size,
                              hipStream_t stream) {
    const float* x  = (const float*)d_in[0];
    const int*   ei = (const int*)d_in[1];
    const float* W1 = (const float*)d_in[2];
    const float* b1 = (const float*)d_in[3];
    const float* W2 = (const float*)d_in[4];
    const float* b2 = (const float*)d_in[5];
    float* out = (float*)d_out;

    const int N = in_sizes[0] / 128;   // 50000
    const int E = in_sizes[1] / 2;     // 800000
    const int* src = ei;
    const int* dst = ei + E;
    const int NB = (N + 1023) / 1024;  // scan blocks (49)
    const int EB1 = (E + 255) / 256;   // edge blocks, 1 edge/thread

    // workspace layout (~56 MB; y regions kept at fp32 size for safety)
    char* ws = (char*)d_ws;
    size_t off = 0;
    int* deg     = (int*)(ws + off); off = align_up(off + (size_t)N * 4, 512);
    int* rowptr  = (int*)(ws + off); off = align_up(off + (size_t)(N + 1) * 4, 512);
    int* fillpos = (int*)(ws + off); off = align_up(off + (size_t)N * 4, 512);
    float* dinv  = (float*)(ws + off); off = align_up(off + (size_t)N * 4, 512);
    int* bsum    = (int*)(ws + off); off = align_up(off + (size_t)NB * 4, 512);
    int* boff    = (int*)(ws + off); off = align_up(off + (size_t)NB * 4, 512);
    int* csrc    = (int*)(ws + off); off = align_up(off + (size_t)E * 4, 512);
    ushort* y1   = (ushort*)(ws + off);                // [N,128] bf16; region reused as y2 bf16 [N,64]
    size_t off_y1 = off; off = align_up(off + (size_t)N * 128 * 4, 512);
    float* h     = (float*)(ws + off); off = align_up(off + (size_t)N * 128 * 4, 512);
    ushort* y2   = (ushort*)(ws + off_y1);
    (void)ws_size; (void)n_in; (void)out_size;

    hipMemsetAsync(deg, 0, (size_t)N * 4, stream);

    count_kernel<<<EB1, 256, 0, stream>>>(dst, deg, E);
    scan_phaseA<<<NB, 256, 0, stream>>>(deg, bsum, N);
    scan_phaseB<<<1, 64, 0, stream>>>(bsum, boff, NB);
    scan_phaseC<<<NB, 256, 0, stream>>>(deg, boff, rowptr, fillpos, dinv, N);
    fill_kernel<<<EB1, 256, 0, stream>>>(src, dst, fillpos, csrc, E);

    // layer 1: gemm writes bf16 y1; aggregation gathers bf16
    gemm_scale<128, 4, true><<<(N + 63) / 64, 256, 0, stream>>>(x, W1, dinv, (void*)y1, N);
    agg_relu128<<<(N + 3) / 4, 256, 0, stream>>>(y1, rowptr, csrc, dinv, b1, h, N);

    // layer 2: gemm writes bf16 y2; aggregation gathers bf16
    gemm_scale<64, 2, true><<<(N + 63) / 64, 256, 0, stream>>>(h, W2, dinv, (void*)y2, N);
    agg_lsm64<<<(N + 3) / 4, 256, 0, stream>>>(y2, rowptr, csrc, dinv, b2, out, N);
}